// Round 9
// baseline (57.605 us; speedup 1.0000x reference)
//
#include <hip/hip_runtime.h>
#include <hip/hip_bf16.h>
#include <stdint.h>

// ---------------------------------------------------------------------------
// SupervisedInfoNCELoss, N=8192, D=128, TAF=0.05
// loss = mean_i [ ln(sum_j exp2(acc_ij)) - diag_i ]   where
//   acc_ij = (zn_i * LOG2E/TAF) . bn_j   in fp8-e4m3 x fp8-e4m3 MFMA
//   diag_i computed EXACTLY in f32. Validated rounds 6-8 (absmax 0.0).
//
// Round 9: occupancy attack. Round-8 post-mortem: fp8 halved matrix+bytes,
// dur unchanged => latency-bound at ~2.3 waves/SIMD (Occupancy 17-31% in ALL
// rounds, far below resource limits). Hypothesis: 1-wave workgroups don't
// pack into CU wave slots. Test: 4 independent SELF-PACED waves per block
// (no barriers; private LDS slice + per-wave vmcnt), grid 1024, 5 blocks/CU
// = 20 waves/CU target. Also split the 8-deep MFMA accumulate chain into
// two 4-chains (acc0+acc1) to shorten per-tile dependent latency.
// NO __launch_bounds__ VGPR cap (r2/r6 spill lesson).
// ---------------------------------------------------------------------------

#define TAF_F 0.05f
constexpr float LOG2E  = 1.4426950408889634f;
constexpr float SCALE  = LOG2E / TAF_F;     // folded into znb8 at normalize

constexpr int N_ROWS     = 8192;
constexpr int D_DIM      = 128;
constexpr int TWO_N      = 16384;
constexpr int NJ         = 32;              // column chunks
constexpr int JCHUNK     = TWO_N / NJ;      // 512 columns per block
constexpr int COL_TILE   = 32;              // B tile staged per step (32x32 MFMA)
constexpr int NTW        = JCHUNK / COL_TILE;   // 16 tiles per wave
constexpr int WAVE_ROWS  = 64;              // rows per wave (2 strips of 32)
constexpr int BLOCK_ROWS = 256;             // 4 waves x 64 rows
constexpr int ROW_BLOCKS = N_ROWS / BLOCK_ROWS; // 32
constexpr int TILE_BYTES = COL_TILE * D_DIM;    // 4 KiB (fp8)

typedef float  f32x16 __attribute__((ext_vector_type(16)));

typedef __attribute__((address_space(3))) uint32_t       lds_u32;
typedef const __attribute__((address_space(1))) uint32_t glb_u32;

#if __has_builtin(__builtin_amdgcn_exp2f)
#define EXP2(x) __builtin_amdgcn_exp2f(x)
#else
#define EXP2(x) exp2f(x)
#endif

// f32 -> OCP e4m3fn, RNE, FTZ below 2^-6.
__device__ inline unsigned char f32_to_e4m3(float f) {
    unsigned u = __float_as_uint(f);
    unsigned sg = (u >> 24) & 0x80u;
    unsigned au = u & 0x7FFFFFFFu;
    if (au < 0x3C800000u) return (unsigned char)sg;   // |f| < 2^-6 -> +-0
    if (au > 0x43E00000u) au = 0x43E00000u;           // clamp to 448
    const unsigned lsb = (au >> 20) & 1u;
    au += 0x0007FFFFu + lsb;                          // RNE to 3 mantissa bits
    int e = (int)(au >> 23) - 127 + 7;
    unsigned m = (au >> 20) & 7u;
    if (e > 15) { e = 15; m = 6u; }                   // re-clamp to 448
    return (unsigned char)(sg | ((unsigned)e << 3) | m);
}

// ---------------------------------------------------------------------------
// Kernel 1: per-row normalize -> fp8 (A side pre-scaled by LOG2E/TAF),
// plus exact f32 diagonal logit. One wave per row; 4 rows per 256-thr block.
// ---------------------------------------------------------------------------
__global__ void normalize_quant_kernel(const float* __restrict__ z,
                                       const float* __restrict__ zp,
                                       const float* __restrict__ znm,
                                       unsigned char* __restrict__ znb8,
                                       unsigned char* __restrict__ bnb8,
                                       float* __restrict__ diag) {
    const int wv   = threadIdx.x >> 6;
    const int lane = threadIdx.x & 63;
    const int i    = blockIdx.x * 4 + wv;

    const float2 vz = *reinterpret_cast<const float2*>(z   + (size_t)i * D_DIM + lane * 2);
    const float2 vp = *reinterpret_cast<const float2*>(zp  + (size_t)i * D_DIM + lane * 2);
    const float2 vn = *reinterpret_cast<const float2*>(znm + (size_t)i * D_DIM + lane * 2);

    float sz  = vz.x * vz.x + vz.y * vz.y;
    float sp  = vp.x * vp.x + vp.y * vp.y;
    float sn  = vn.x * vn.x + vn.y * vn.y;
    float szp = vz.x * vp.x + vz.y * vp.y;
#pragma unroll
    for (int o = 32; o >= 1; o >>= 1) {
        sz  += __shfl_xor(sz, o);
        sp  += __shfl_xor(sp, o);
        sn  += __shfl_xor(sn, o);
        szp += __shfl_xor(szp, o);
    }
    const float rz0 = 1.0f / fmaxf(sqrtf(sz), 1e-8f);
    const float rzs = rz0 * SCALE;                      // pre-scaled A
    const float rp  = 1.0f / fmaxf(sqrtf(sp), 1e-8f);
    const float rn  = 1.0f / fmaxf(sqrtf(sn), 1e-8f);

    const unsigned short za = (unsigned short)f32_to_e4m3(vz.x * rzs)
                            | ((unsigned short)f32_to_e4m3(vz.y * rzs) << 8);
    const unsigned short pa = (unsigned short)f32_to_e4m3(vp.x * rp)
                            | ((unsigned short)f32_to_e4m3(vp.y * rp) << 8);
    const unsigned short na = (unsigned short)f32_to_e4m3(vn.x * rn)
                            | ((unsigned short)f32_to_e4m3(vn.y * rn) << 8);
    *reinterpret_cast<unsigned short*>(znb8 + (size_t)i * D_DIM + lane * 2)            = za;
    *reinterpret_cast<unsigned short*>(bnb8 + (size_t)i * D_DIM + lane * 2)            = pa;
    *reinterpret_cast<unsigned short*>(bnb8 + (size_t)(N_ROWS + i) * D_DIM + lane * 2) = na;
    if (lane == 0) diag[i] = szp * rz0 * rp * (1.0f / TAF_F);
}

// ---------------------------------------------------------------------------
// Kernel 2: fused fp8 GEMM + partial sum-of-exp2. 4 independent self-paced
// waves per 256-thread block, NO barriers. grid = 1024 (XCD-swizzled).
// Each wave: 64 rows (2 strips of 32) x 512 cols in 16 tiles of 32 cols,
// private 2x4KB LDS dbuf, per-wave vmcnt(4) pacing (1 DMA-batch in flight).
// MFMA accumulate chain split 8 -> 4+4 (acc0/acc1) for shorter dep latency.
// mfma_f32_32x32x16_fp8_fp8: A/B row|col = lane&31, k = (lane>>5)*8+e;
// C/D col = lane&31, row = (reg&3) + 8*(reg>>2) + 4*(lane>>5)  [m74/m101].
// ---------------------------------------------------------------------------
__global__ __launch_bounds__(256) void partial_lse_kernel(
        const unsigned char* __restrict__ znb8,
        const unsigned char* __restrict__ bnb8,
        float* __restrict__ partial) {
    __shared__ __align__(16) unsigned char lds[4 * 2 * TILE_BYTES];  // 32 KiB

    const int tid  = threadIdx.x;
    const int lane = tid & 63;
    const int wv   = tid >> 6;             // 0..3, fully independent wave
    const int l31  = lane & 31;
    const int l5   = lane >> 5;

    // T1 XCD swizzle (bijective, 1024 % 8 == 0)
    const int bid = blockIdx.x;
    const int swz = (bid & 7) * 128 + (bid >> 3);
    const int rowBlk = swz & (ROW_BLOCKS - 1);
    const int jChunk = swz >> 5;
    const int rowBase = rowBlk * BLOCK_ROWS + wv * WAVE_ROWS;
    const int jBase   = jChunk * JCHUNK;

    unsigned char* myLds = lds + wv * (2 * TILE_BYTES);   // private slice

    // stage one 32-col tile (4KB = 256 x 16B chunks): 64 lanes x 4 DMAs
    auto stageTile = [&](int tile, int buf) {
        const unsigned char* srcTile = bnb8 + (size_t)(jBase + tile * COL_TILE) * D_DIM;
        unsigned char* ldsw = myLds + buf * TILE_BYTES;
#pragma unroll
        for (int it = 0; it < 4; ++it) {
            const int s = it * 64 + lane;                      // chunk (col=s>>3, q=s&7)
            const int g = (s & ~7) | ((s & 7) ^ ((s >> 3) & 7));  // src (col, q^(col&7))
            __builtin_amdgcn_global_load_lds(
                (glb_u32*)(srcTile + (size_t)g * 16),
                (lds_u32*)(ldsw + s * 16), 16, 0, 0);
        }
    };

    // A fragments: 2 strips x 8 K-steps, held in VGPRs the whole kernel.
    long a[2][8];
#pragma unroll
    for (int st = 0; st < 2; ++st)
#pragma unroll
        for (int kk = 0; kk < 8; ++kk)
            a[st][kk] = *reinterpret_cast<const long*>(
                znb8 + (size_t)(rowBase + st * 32 + l31) * D_DIM + kk * 16 + l5 * 8);

    float sums[2][16];
#pragma unroll
    for (int st = 0; st < 2; ++st)
#pragma unroll
        for (int e = 0; e < 16; ++e) sums[st][e] = 0.0f;

    stageTile(0, 0);   // prologue

    for (int t = 0; t < NTW; ++t) {
        // issue next tile's 4 DMAs (wrap at end: dead but uniform accounting)
        stageTile((t + 1) & (NTW - 1), (t + 1) & 1);
        // retire exactly tile t's 4 DMAs; keep tile t+1's 4 in flight
        asm volatile("s_waitcnt vmcnt(4)" ::: "memory");

        const unsigned char* ldsr = myLds + (t & 1) * TILE_BYTES;
        long b[8];
#pragma unroll
        for (int kk = 0; kk < 8; ++kk) {
            const int q = kk ^ (l31 & 7);                    // swizzled 16B chunk
            b[kk] = *reinterpret_cast<const long*>(ldsr + l31 * D_DIM + q * 16 + l5 * 8);
        }
#pragma unroll
        for (int st = 0; st < 2; ++st) {
            f32x16 acc0 = {}, acc1 = {};                     // two independent 4-chains
#pragma unroll
            for (int kk = 0; kk < 4; ++kk) {
                acc0 = __builtin_amdgcn_mfma_f32_32x32x16_fp8_fp8(a[st][kk],     b[kk],     acc0, 0, 0, 0);
                acc1 = __builtin_amdgcn_mfma_f32_32x32x16_fp8_fp8(a[st][kk + 4], b[kk + 4], acc1, 0, 0, 0);
            }
#pragma unroll
            for (int e = 0; e < 16; ++e)
                sums[st][e] += EXP2(acc0[e] + acc1[e]);      // 1 add + 1 trans + 1 add
        }
    }
    // drain the dead wrap-around DMAs before wave exit
    asm volatile("s_waitcnt vmcnt(0)" ::: "memory");

    // reduce each sum over the 32 column-holding lanes (lane&31)
#pragma unroll
    for (int st = 0; st < 2; ++st)
#pragma unroll
        for (int e = 0; e < 16; ++e) {
            float v = sums[st][e];
            v += __shfl_xor(v, 1);
            v += __shfl_xor(v, 2);
            v += __shfl_xor(v, 4);
            v += __shfl_xor(v, 8);
            v += __shfl_xor(v, 16);
            sums[st][e] = v;
        }
    if (l31 == 0) {   // lanes 0 and 32 (l5 = 0/1) hold different rows
#pragma unroll
        for (int st = 0; st < 2; ++st)
#pragma unroll
            for (int e = 0; e < 16; ++e) {
                const int row = rowBase + st * 32 + (e & 3) + 8 * (e >> 2) + 4 * l5;
                partial[(size_t)row * NJ + jChunk] = sums[st][e];
            }
    }
}

// ---------------------------------------------------------------------------
// Kernel 3: per-row merge + ln + diag subtract; per-block partial sums.
// ---------------------------------------------------------------------------
__global__ void finalize_rows_kernel(const float* __restrict__ partial,
                                     const float* __restrict__ diag,
                                     float* __restrict__ blocksum) {
    const int t = threadIdx.x;
    const int r = blockIdx.x * 256 + t;
    const float4* prow = reinterpret_cast<const float4*>(partial + (size_t)r * NJ);
    float se = 0.0f;
#pragma unroll
    for (int c = 0; c < NJ / 4; ++c) {
        const float4 v = prow[c];
        se += (v.x + v.y) + (v.z + v.w);
    }
    float res = logf(se) - diag[r];
#pragma unroll
    for (int o = 32; o >= 1; o >>= 1) res += __shfl_xor(res, o);
    __shared__ float red[4];
    if ((t & 63) == 0) red[t >> 6] = res;
    __syncthreads();
    if (t == 0) blocksum[blockIdx.x] = red[0] + red[1] + red[2] + red[3];
}

// ---------------------------------------------------------------------------
// Kernel 4: final reduce of 32 block sums -> mean -> d_out[0].
// ---------------------------------------------------------------------------
__global__ void final_kernel(const float* __restrict__ blocksum,
                             float* __restrict__ out) {
    const int t = threadIdx.x;  // 64 threads
    float v = (t < 32) ? blocksum[t] : 0.0f;
#pragma unroll
    for (int o = 32; o >= 1; o >>= 1) v += __shfl_xor(v, o);
    if (t == 0) out[0] = v * (1.0f / (float)N_ROWS);
}

// ---------------------------------------------------------------------------
extern "C" void kernel_launch(void* const* d_in, const int* in_sizes, int n_in,
                              void* d_out, int out_size, void* d_ws, size_t ws_size,
                              hipStream_t stream) {
    const float* z   = (const float*)d_in[0];
    const float* zp  = (const float*)d_in[1];
    const float* znm = (const float*)d_in[2];

    char* ws = (char*)d_ws;
    // workspace layout (bytes):
    //   znb8    : [8192][128] fp8             @ 0         (1,048,576)
    //   bnb8    : [16384][128] fp8            @ 1,048,576 (2,097,152)
    //   diag    : [8192] f32                  @ 3,145,728 (32,768)
    //   partial : [8192][NJ=32] f32           @ 3,178,496 (1,048,576)
    //   blocksum: [32] f32                    @ 4,227,072 (128)
    unsigned char* znb8 = (unsigned char*)(ws);
    unsigned char* bnb8 = (unsigned char*)(ws + 1048576);
    float* diag     = (float*)(ws + 3145728);
    float* partial  = (float*)(ws + 3178496);
    float* blocksum = (float*)(ws + 4227072);
    float* out      = (float*)d_out;

    normalize_quant_kernel<<<N_ROWS / 4, 256, 0, stream>>>(z, zp, znm, znb8, bnb8, diag);
    partial_lse_kernel<<<ROW_BLOCKS * NJ, 256, 0, stream>>>(znb8, bnb8, partial);
    finalize_rows_kernel<<<N_ROWS / 256, 256, 0, stream>>>(partial, diag, blocksum);
    final_kernel<<<1, 64, 0, stream>>>(blocksum, out);
}